// Round 6
// baseline (404.424 us; speedup 1.0000x reference)
//
#include <hip/hip_runtime.h>
#include <cstdint>

typedef __bf16 bf16;
typedef __bf16 bf16x8 __attribute__((ext_vector_type(8)));
typedef __bf16 bf16x4 __attribute__((ext_vector_type(4)));
typedef float f32x4 __attribute__((ext_vector_type(4)));

#define DIMN 2048
#define SEQ  2048
#define NH   16
#define HD   128

// -------- async global->LDS 16B helper (m97 pattern) --------
__device__ __forceinline__ void gld_lds16(const bf16* g, bf16* l) {
    __builtin_amdgcn_global_load_lds(
        (const __attribute__((address_space(1))) void*)g,
        (__attribute__((address_space(3))) void*)l,
        16, 0, 0);
}

// -------- all fp32->bf16 casts in ONE launch --------
__global__ __launch_bounds__(256) void cast_all(
    const float* __restrict__ x,
    const float* __restrict__ wq, const float* __restrict__ wk,
    const float* __restrict__ wv, const float* __restrict__ wo,
    bf16* __restrict__ xb,
    bf16* __restrict__ wqb, bf16* __restrict__ wkb,
    bf16* __restrict__ wvb, bf16* __restrict__ wob)
{
    int id = blockIdx.x;
    const float* src; bf16* dst; int i;
    if (id < 8192) { src = x; dst = xb; i = id * 256 + threadIdx.x; }
    else {
        id -= 8192;
        int w = id >> 12; id &= 4095;
        src = (w == 0) ? wq : (w == 1) ? wk : (w == 2) ? wv : wo;
        dst = (w == 0) ? wqb : (w == 1) ? wkb : (w == 2) ? wvb : wob;
        i = id * 256 + threadIdx.x;
    }
    float4 v = ((const float4*)src)[i];
    bf16x4 o;
    o[0] = (bf16)v.x; o[1] = (bf16)v.y; o[2] = (bf16)v.z; o[3] = (bf16)v.w;
    ((bf16x4*)dst)[i] = o;
}

// -------- GEMM: C[m][n] = sum_k A[m][k]*B[n][k] + bias[n]
// 128x128 tile, BK=64 (32 MFMA/barrier), seg-XOR swizzled LDS (conflict-free).
// EPI: 0 = bf16 row-major, 1 = f32 row-major, 2 = bf16 transposed V^T layout
//      vt[(b*DIMN + col)*SEQ + s]  (deletes the separate transpose pass).
template<int EPI>
__global__ __launch_bounds__(256) void gemm_bt(
    const bf16* __restrict__ A, const bf16* __restrict__ Bw,
    const float* __restrict__ bias, void* __restrict__ Cout)
{
    const int K = DIMN, N = DIMN;
    __shared__ __attribute__((aligned(16))) bf16 As[128 * 64];
    __shared__ __attribute__((aligned(16))) bf16 Bs[128 * 64];

    const int t    = threadIdx.x;
    const int lane = t & 63, wave = t >> 6;
    const int l15  = lane & 15, quad = lane >> 4;
    const int wm   = (wave >> 1) * 64, wn = (wave & 1) * 64;
    const long bm  = (long)blockIdx.y * 128;
    const long bn  = (long)blockIdx.x * 128;

    const bf16* agp[4]; const bf16* bgp[4]; bf16* asd[4]; bf16* bsd[4];
#pragma unroll
    for (int it = 0; it < 4; it++) {
        int fs  = it * 256 + t;
        int row = fs >> 3;
        int gs  = (fs & 7) ^ (row & 7);
        agp[it] = A  + (bm + row) * (long)K + gs * 8;
        bgp[it] = Bw + (bn + row) * (long)K + gs * 8;
        asd[it] = As + fs * 8;
        bsd[it] = Bs + fs * 8;
    }
    const int swl = l15 & 7;

    f32x4 acc[4][4] = {};

    for (int k0 = 0; k0 < K; k0 += 64) {
#pragma unroll
        for (int it = 0; it < 4; it++) {
            gld_lds16(agp[it] + k0, asd[it]);
            gld_lds16(bgp[it] + k0, bsd[it]);
        }
        __syncthreads();

#pragma unroll
        for (int ks2 = 0; ks2 < 2; ks2++) {
            const int sw = ((ks2 * 4 + quad) ^ swl) * 8;
            bf16x8 af[4], bfr[4];
#pragma unroll
            for (int i = 0; i < 4; i++)
                af[i] = *(const bf16x8*)(As + (wm + i * 16 + l15) * 64 + sw);
#pragma unroll
            for (int j = 0; j < 4; j++)
                bfr[j] = *(const bf16x8*)(Bs + (wn + j * 16 + l15) * 64 + sw);
#pragma unroll
            for (int i = 0; i < 4; i++)
#pragma unroll
                for (int j = 0; j < 4; j++)
                    acc[i][j] = __builtin_amdgcn_mfma_f32_16x16x32_bf16(af[i], bfr[j], acc[i][j], 0, 0, 0);
        }
        __syncthreads();
    }

    // epilogue: D row = quad*4+reg, col = l15 (m89-verified)
#pragma unroll
    for (int j = 0; j < 4; j++) {
        const long col = bn + wn + j * 16 + l15;
        const float bv = bias[col];
#pragma unroll
        for (int i = 0; i < 4; i++) {
            const long row0 = bm + wm + i * 16 + quad * 4;
            if (EPI == 2) {
                // V^T: vt[(b*DIMN + col)*SEQ + s], 4 consecutive s -> b64 store
                const long b = row0 >> 11, s0 = row0 & 2047;
                bf16x4 pk;
#pragma unroll
                for (int r = 0; r < 4; r++) pk[r] = (bf16)(acc[i][j][r] + bv);
                *(bf16x4*)((bf16*)Cout + (b * DIMN + col) * (long)SEQ + s0) = pk;
            } else {
#pragma unroll
                for (int r = 0; r < 4; r++) {
                    float v = acc[i][j][r] + bv;
                    if (EPI == 1) ((float*)Cout)[(row0 + r) * N + col] = v;
                    else          ((bf16*)Cout)[(row0 + r) * N + col] = (bf16)v;
                }
            }
        }
    }
}

// -------- fused RMSNorm + RoPE; Q pre-scaled by 1/sqrt(HD) --------
__global__ __launch_bounds__(256) void rmsnorm_rope(
    bf16* __restrict__ q, bf16* __restrict__ k,
    const float* __restrict__ gq, const float* __restrict__ gk,
    const float* __restrict__ freqs)
{
    const int id = blockIdx.x;
    const int qk  = id >> 12;
    const int row = id & 4095;                 // b*SEQ + s
    bf16* ptr = qk ? k : q;
    const float* g = qk ? gk : gq;
    const float osc = qk ? 1.0f : 0.08838834764831845f;
    const int s = row & (SEQ - 1);
    const int t = threadIdx.x;
    const int lane = t & 63, wave = t >> 6;

    bf16* base = ptr + (long)row * DIMN + t * 8;
    bf16x8 raw = *(const bf16x8*)base;
    float v[8]; float ss = 0.f;
#pragma unroll
    for (int j = 0; j < 8; j++) { v[j] = (float)raw[j]; ss += v[j] * v[j]; }
#pragma unroll
    for (int off = 32; off; off >>= 1) ss += __shfl_xor(ss, off, 64);
    __shared__ float red[4];
    if (lane == 0) red[wave] = ss;
    __syncthreads();
    float tot = red[0] + red[1] + red[2] + red[3];
    float rn = rsqrtf(tot * (1.0f / DIMN) + 1e-6f);

    const int e0 = t * 8;
    bf16x8 o;
#pragma unroll
    for (int pp = 0; pp < 4; pp++) {
        int e = e0 + pp * 2;
        float xr = v[pp * 2]     * rn * g[e];
        float xi = v[pp * 2 + 1] * rn * g[e + 1];
        int lc = (e >> 1) & 63;
        float cr = freqs[s * 128 + lc * 2];
        float ci = freqs[s * 128 + lc * 2 + 1];
        o[pp * 2]     = (bf16)((xr * cr - xi * ci) * osc);
        o[pp * 2 + 1] = (bf16)((xr * ci + xi * cr) * osc);
    }
    *(bf16x8*)base = o;
}

// -------- flash-style attention v4: 8 waves x BM=32/wave, dbuf K/V with the
// prefetch issued AFTER the barrier (loads stay in flight across the whole
// compute phase; next iter's barrier-drain is ~free — the r5 version issued
// before the barrier, so the compiler's vmcnt(0)+s_barrier drained the fresh
// prefetch every iter and exposed full memory latency).
// grid (x=bh, y=qt): 8 qt-blocks sharing a head's K/V land on one XCD.
__global__ __launch_bounds__(512, 2) void attention(
    const bf16* __restrict__ Q, const bf16* __restrict__ Kb,
    const bf16* __restrict__ Vt, bf16* __restrict__ O)
{
    __shared__ __attribute__((aligned(16))) bf16 Ksh[2][64 * 128];   // [kr][d], seg^=(kr&15)
    __shared__ __attribute__((aligned(16))) bf16 Vsh[2][128 * 64];   // [d][kr], seg^=(d&7)
    __shared__ __attribute__((aligned(16))) bf16 Psh[8][32 * 72];    // per-wave P[m][kr]
    __shared__ float Lsh[8][32];

    const int t = threadIdx.x;
    const int lane = t & 63, w = t >> 6;
    const int l15 = lane & 15, quad = lane >> 4;
    const int bh = blockIdx.x, b = bh >> 4, h = bh & 15;
    const int qt = blockIdx.y;
    const long qrow0 = (long)b * SEQ + qt * 256 + w * 32;
    const bf16* qbase = Q  + qrow0 * DIMN + h * HD;
    const bf16* kbase = Kb + (long)b * SEQ * DIMN + h * HD;
    const bf16* vbase = Vt + (long)bh * HD * SEQ;

    // Q fragments resident (pre-scaled by rmsnorm_rope): B[m=l15][k=quad*8+j]
    bf16x8 qf[2][4];
#pragma unroll
    for (int im = 0; im < 2; im++)
#pragma unroll
        for (int kd = 0; kd < 4; kd++)
            qf[im][kd] = *(const bf16x8*)(qbase + (long)(im * 16 + l15) * DIMN + kd * 32 + quad * 8);

    long koff[2], voff[2];
#pragma unroll
    for (int it = 0; it < 2; it++) {
        int fs = it * 512 + t;
        int kr = fs >> 4, kp = fs & 15;
        koff[it] = (long)kr * DIMN + (kp ^ (kr & 15)) * 8;
        int dr = fs >> 3, vp = fs & 7;
        voff[it] = (long)dr * SEQ + (vp ^ (dr & 7)) * 8;
    }

    f32x4 o_acc[2][8] = {};
    float Lt[2] = {0.f, 0.f};

    // prefetch kt=0 into buffer 0
#pragma unroll
    for (int it = 0; it < 2; it++) {
        gld_lds16(kbase + koff[it], &Ksh[0][(it * 512 + t) * 8]);
        gld_lds16(vbase + voff[it], &Vsh[0][(it * 512 + t) * 8]);
    }

    for (int kt = 0; kt < 32; kt++) {
        const int cur = kt & 1;
        // barrier FIRST: drains cur's DMA (needed anyway) and guarantees all
        // waves finished reading buf^1 (last iter's cur) before we overwrite it
        __syncthreads();
        if (kt < 31) {
            const bf16* kg = kbase + (long)((kt + 1) * 64) * DIMN;
            const bf16* vg = vbase + (kt + 1) * 64;
#pragma unroll
            for (int it = 0; it < 2; it++) {
                gld_lds16(kg + koff[it], &Ksh[cur ^ 1][(it * 512 + t) * 8]);
                gld_lds16(vg + voff[it], &Vsh[cur ^ 1][(it * 512 + t) * 8]);
            }
        }
        const bf16* K0 = Ksh[cur];
        const bf16* V0 = Vsh[cur];

        // ---- S^T = K Q^T : D[kr][m] ----
        f32x4 st[4][2] = {};
#pragma unroll
        for (int jk = 0; jk < 4; jk++)
#pragma unroll
            for (int kd = 0; kd < 4; kd++) {
                bf16x8 kf = *(const bf16x8*)(K0 + (jk * 16 + l15) * 128 + (((kd * 4 + quad) ^ l15) & 15) * 8);
                st[jk][0] = __builtin_amdgcn_mfma_f32_16x16x32_bf16(kf, qf[0][kd], st[jk][0], 0, 0, 0);
                st[jk][1] = __builtin_amdgcn_mfma_f32_16x16x32_bf16(kf, qf[1][kd], st[jk][1], 0, 0, 0);
            }

        // ---- exp + P->LDS (b64) + per-lane partial L (reduction deferred) ----
#pragma unroll
        for (int im = 0; im < 2; im++) {
            float part = 0.f;
#pragma unroll
            for (int jk = 0; jk < 4; jk++) {
                bf16x4 pk;
#pragma unroll
                for (int r = 0; r < 4; r++) {
                    float e = __expf(st[jk][im][r]);
                    part += e;
                    pk[r] = (bf16)e;
                }
                *(bf16x4*)(Psh[w] + (im * 16 + l15) * 72 + jk * 16 + quad * 4) = pk;
            }
            Lt[im] += part;
        }
        // no barrier: Psh[w] wave-private, LDS in-order per wave

        // ---- O += P V ----
#pragma unroll
        for (int kd2 = 0; kd2 < 2; kd2++) {
            bf16x8 pa[2];
            pa[0] = *(const bf16x8*)(Psh[w] + (l15)      * 72 + kd2 * 32 + quad * 8);
            pa[1] = *(const bf16x8*)(Psh[w] + (16 + l15) * 72 + kd2 * 32 + quad * 8);
#pragma unroll
            for (int dj = 0; dj < 8; dj++) {
                bf16x8 vfr = *(const bf16x8*)(V0 + (dj * 16 + l15) * 64 + (((kd2 * 4 + quad) ^ l15) & 7) * 8);
                o_acc[0][dj] = __builtin_amdgcn_mfma_f32_16x16x32_bf16(pa[0], vfr, o_acc[0][dj], 0, 0, 0);
                o_acc[1][dj] = __builtin_amdgcn_mfma_f32_16x16x32_bf16(pa[1], vfr, o_acc[1][dj], 0, 0, 0);
            }
        }
        // no end-of-iter barrier: next iter's top barrier handles both fences
    }

    // deferred L reduction (butterfly over quads); Lsh is wave-private -> no barrier
#pragma unroll
    for (int im = 0; im < 2; im++) {
        Lt[im] += __shfl_xor(Lt[im], 16, 64);
        Lt[im] += __shfl_xor(Lt[im], 32, 64);
    }
    if (quad == 0) { Lsh[w][l15] = Lt[0]; Lsh[w][16 + l15] = Lt[1]; }

    // normalize + write (aliases Q buffer: block writes only rows/cols it alone read)
#pragma unroll
    for (int im = 0; im < 2; im++)
#pragma unroll
        for (int r = 0; r < 4; r++) {
            float inv = 1.0f / Lsh[w][im * 16 + quad * 4 + r];
            long orow = qrow0 + im * 16 + quad * 4 + r;
#pragma unroll
            for (int dj = 0; dj < 8; dj++)
                O[orow * DIMN + h * HD + dj * 16 + l15] = (bf16)(o_acc[im][dj][r] * inv);
        }
}

extern "C" void kernel_launch(void* const* d_in, const int* in_sizes, int n_in,
                              void* d_out, int out_size, void* d_ws, size_t ws_size,
                              hipStream_t stream) {
    const float* x     = (const float*)d_in[0];
    const float* freqs = (const float*)d_in[1];
    const float* wq    = (const float*)d_in[2];
    const float* bq    = (const float*)d_in[3];
    const float* wk    = (const float*)d_in[4];
    const float* bk    = (const float*)d_in[5];
    const float* wv    = (const float*)d_in[6];
    const float* bv    = (const float*)d_in[7];
    const float* wo    = (const float*)d_in[8];
    const float* bo    = (const float*)d_in[9];
    const float* gq    = (const float*)d_in[10];
    const float* gk    = (const float*)d_in[11];
    float* out = (float*)d_out;

    const size_t MAT  = (size_t)4096 * 2048 * 2;   // 16 MiB
    const size_t WMAT = (size_t)2048 * 2048 * 2;   // 8 MiB
    char* p = (char*)d_ws;
    bf16* xb  = (bf16*)p; p += MAT;
    bf16* wqb = (bf16*)p; p += WMAT;
    bf16* wkb = (bf16*)p; p += WMAT;
    bf16* wvb = (bf16*)p; p += WMAT;
    bf16* wob = (bf16*)p; p += WMAT;
    bf16* qb  = (bf16*)p; p += MAT;
    bf16* kb  = (bf16*)p; p += MAT;
    bf16* vt  = (bf16*)p; p += MAT;
    bf16* attn = qb;   // alias (safe: per-block exclusive row/col regions)

    cast_all<<<24576, 256, 0, stream>>>(x, wq, wk, wv, wo, xb, wqb, wkb, wvb, wob);

    // Q, K, V projections (V written directly as V^T)
    gemm_bt<0><<<dim3(16, 32), 256, 0, stream>>>(xb, wqb, bq, qb);
    gemm_bt<0><<<dim3(16, 32), 256, 0, stream>>>(xb, wkb, bk, kb);
    gemm_bt<2><<<dim3(16, 32), 256, 0, stream>>>(xb, wvb, bv, vt);

    rmsnorm_rope<<<8192, 256, 0, stream>>>(qb, kb, gq, gk, freqs);
    attention<<<dim3(32, 8), 512, 0, stream>>>(qb, kb, vt, attn);
    gemm_bt<1><<<dim3(16, 32), 256, 0, stream>>>(attn, wob, bo, out);
}

// Round 7
// 396.168 us; speedup vs baseline: 1.0208x; 1.0208x over previous
//
#include <hip/hip_runtime.h>
#include <cstdint>

typedef __bf16 bf16;
typedef __bf16 bf16x8 __attribute__((ext_vector_type(8)));
typedef __bf16 bf16x4 __attribute__((ext_vector_type(4)));
typedef float f32x4 __attribute__((ext_vector_type(4)));

#define DIMN 2048
#define SEQ  2048
#define NH   16
#define HD   128

// -------- async global->LDS 16B helper (m97 pattern) --------
__device__ __forceinline__ void gld_lds16(const bf16* g, bf16* l) {
    __builtin_amdgcn_global_load_lds(
        (const __attribute__((address_space(1))) void*)g,
        (__attribute__((address_space(3))) void*)l,
        16, 0, 0);
}

// -------- all fp32->bf16 casts in ONE launch --------
__global__ __launch_bounds__(256) void cast_all(
    const float* __restrict__ x,
    const float* __restrict__ wq, const float* __restrict__ wk,
    const float* __restrict__ wv, const float* __restrict__ wo,
    bf16* __restrict__ xb,
    bf16* __restrict__ wqb, bf16* __restrict__ wkb,
    bf16* __restrict__ wvb, bf16* __restrict__ wob)
{
    int id = blockIdx.x;
    const float* src; bf16* dst; int i;
    if (id < 8192) { src = x; dst = xb; i = id * 256 + threadIdx.x; }
    else {
        id -= 8192;
        int w = id >> 12; id &= 4095;
        src = (w == 0) ? wq : (w == 1) ? wk : (w == 2) ? wv : wo;
        dst = (w == 0) ? wqb : (w == 1) ? wkb : (w == 2) ? wvb : wob;
        i = id * 256 + threadIdx.x;
    }
    float4 v = ((const float4*)src)[i];
    bf16x4 o;
    o[0] = (bf16)v.x; o[1] = (bf16)v.y; o[2] = (bf16)v.z; o[3] = (bf16)v.w;
    ((bf16x4*)dst)[i] = o;
}

// -------- fused QKV GEMM: one 1536-block dispatch (r5's occupancy/tail win),
// z selects weight set; z==2 (V) writes the transposed V^T epilogue directly
// (r6's deleted-transpose win). 128x128 tile, BK=64, seg-XOR swizzled LDS.
__global__ __launch_bounds__(256) void gemm_qkv(
    const bf16* __restrict__ A,
    const bf16* __restrict__ Bw0, const bf16* __restrict__ Bw1, const bf16* __restrict__ Bw2,
    const float* __restrict__ bias0, const float* __restrict__ bias1, const float* __restrict__ bias2,
    bf16* __restrict__ C0, bf16* __restrict__ C1, bf16* __restrict__ C2)
{
    const int K = DIMN, N = DIMN;
    const int z = blockIdx.z;
    const bf16* Bw = Bw0; const float* bias = bias0; bf16* Cout = C0;
    if (z == 1) { Bw = Bw1; bias = bias1; Cout = C1; }
    if (z == 2) { Bw = Bw2; bias = bias2; Cout = C2; }

    __shared__ __attribute__((aligned(16))) bf16 As[128 * 64];
    __shared__ __attribute__((aligned(16))) bf16 Bs[128 * 64];

    const int t    = threadIdx.x;
    const int lane = t & 63, wave = t >> 6;
    const int l15  = lane & 15, quad = lane >> 4;
    const int wm   = (wave >> 1) * 64, wn = (wave & 1) * 64;
    const long bm  = (long)blockIdx.y * 128;
    const long bn  = (long)blockIdx.x * 128;

    const bf16* agp[4]; const bf16* bgp[4]; bf16* asd[4]; bf16* bsd[4];
#pragma unroll
    for (int it = 0; it < 4; it++) {
        int fs  = it * 256 + t;
        int row = fs >> 3;
        int gs  = (fs & 7) ^ (row & 7);
        agp[it] = A  + (bm + row) * (long)K + gs * 8;
        bgp[it] = Bw + (bn + row) * (long)K + gs * 8;
        asd[it] = As + fs * 8;
        bsd[it] = Bs + fs * 8;
    }
    const int swl = l15 & 7;

    f32x4 acc[4][4] = {};

    for (int k0 = 0; k0 < K; k0 += 64) {
#pragma unroll
        for (int it = 0; it < 4; it++) {
            gld_lds16(agp[it] + k0, asd[it]);
            gld_lds16(bgp[it] + k0, bsd[it]);
        }
        __syncthreads();

#pragma unroll
        for (int ks2 = 0; ks2 < 2; ks2++) {
            const int sw = ((ks2 * 4 + quad) ^ swl) * 8;
            bf16x8 af[4], bfr[4];
#pragma unroll
            for (int i = 0; i < 4; i++)
                af[i] = *(const bf16x8*)(As + (wm + i * 16 + l15) * 64 + sw);
#pragma unroll
            for (int j = 0; j < 4; j++)
                bfr[j] = *(const bf16x8*)(Bs + (wn + j * 16 + l15) * 64 + sw);
#pragma unroll
            for (int i = 0; i < 4; i++)
#pragma unroll
                for (int j = 0; j < 4; j++)
                    acc[i][j] = __builtin_amdgcn_mfma_f32_16x16x32_bf16(af[i], bfr[j], acc[i][j], 0, 0, 0);
        }
        __syncthreads();
    }

    // epilogue: D row = quad*4+reg, col = l15 (m89-verified); wave-uniform z-branch
    if (z == 2) {
        // V^T: vt[(b*DIMN + col)*SEQ + s], 4 consecutive s -> b64 store
#pragma unroll
        for (int j = 0; j < 4; j++) {
            const long col = bn + wn + j * 16 + l15;
            const float bv = bias[col];
#pragma unroll
            for (int i = 0; i < 4; i++) {
                const long row0 = bm + wm + i * 16 + quad * 4;
                const long b = row0 >> 11, s0 = row0 & 2047;
                bf16x4 pk;
#pragma unroll
                for (int r = 0; r < 4; r++) pk[r] = (bf16)(acc[i][j][r] + bv);
                *(bf16x4*)(Cout + (b * DIMN + col) * (long)SEQ + s0) = pk;
            }
        }
    } else {
#pragma unroll
        for (int j = 0; j < 4; j++) {
            const long col = bn + wn + j * 16 + l15;
            const float bv = bias[col];
#pragma unroll
            for (int i = 0; i < 4; i++) {
                const long row0 = bm + wm + i * 16 + quad * 4;
#pragma unroll
                for (int r = 0; r < 4; r++)
                    Cout[(row0 + r) * N + col] = (bf16)(acc[i][j][r] + bv);
            }
        }
    }
}

// -------- out-projection GEMM (fp32 epilogue) --------
__global__ __launch_bounds__(256) void gemm_out(
    const bf16* __restrict__ A, const bf16* __restrict__ Bw,
    const float* __restrict__ bias, float* __restrict__ Cout)
{
    const int K = DIMN, N = DIMN;
    __shared__ __attribute__((aligned(16))) bf16 As[128 * 64];
    __shared__ __attribute__((aligned(16))) bf16 Bs[128 * 64];

    const int t    = threadIdx.x;
    const int lane = t & 63, wave = t >> 6;
    const int l15  = lane & 15, quad = lane >> 4;
    const int wm   = (wave >> 1) * 64, wn = (wave & 1) * 64;
    const long bm  = (long)blockIdx.y * 128;
    const long bn  = (long)blockIdx.x * 128;

    const bf16* agp[4]; const bf16* bgp[4]; bf16* asd[4]; bf16* bsd[4];
#pragma unroll
    for (int it = 0; it < 4; it++) {
        int fs  = it * 256 + t;
        int row = fs >> 3;
        int gs  = (fs & 7) ^ (row & 7);
        agp[it] = A  + (bm + row) * (long)K + gs * 8;
        bgp[it] = Bw + (bn + row) * (long)K + gs * 8;
        asd[it] = As + fs * 8;
        bsd[it] = Bs + fs * 8;
    }
    const int swl = l15 & 7;

    f32x4 acc[4][4] = {};

    for (int k0 = 0; k0 < K; k0 += 64) {
#pragma unroll
        for (int it = 0; it < 4; it++) {
            gld_lds16(agp[it] + k0, asd[it]);
            gld_lds16(bgp[it] + k0, bsd[it]);
        }
        __syncthreads();

#pragma unroll
        for (int ks2 = 0; ks2 < 2; ks2++) {
            const int sw = ((ks2 * 4 + quad) ^ swl) * 8;
            bf16x8 af[4], bfr[4];
#pragma unroll
            for (int i = 0; i < 4; i++)
                af[i] = *(const bf16x8*)(As + (wm + i * 16 + l15) * 64 + sw);
#pragma unroll
            for (int j = 0; j < 4; j++)
                bfr[j] = *(const bf16x8*)(Bs + (wn + j * 16 + l15) * 64 + sw);
#pragma unroll
            for (int i = 0; i < 4; i++)
#pragma unroll
                for (int j = 0; j < 4; j++)
                    acc[i][j] = __builtin_amdgcn_mfma_f32_16x16x32_bf16(af[i], bfr[j], acc[i][j], 0, 0, 0);
        }
        __syncthreads();
    }

#pragma unroll
    for (int j = 0; j < 4; j++) {
        const long col = bn + wn + j * 16 + l15;
        const float bv = bias[col];
#pragma unroll
        for (int i = 0; i < 4; i++) {
            const long row0 = bm + wm + i * 16 + quad * 4;
#pragma unroll
            for (int r = 0; r < 4; r++)
                Cout[(row0 + r) * N + col] = acc[i][j][r] + bv;
        }
    }
}

// -------- fused RMSNorm + RoPE; Q pre-scaled by 1/sqrt(HD) --------
__global__ __launch_bounds__(256) void rmsnorm_rope(
    bf16* __restrict__ q, bf16* __restrict__ k,
    const float* __restrict__ gq, const float* __restrict__ gk,
    const float* __restrict__ freqs)
{
    const int id = blockIdx.x;
    const int qk  = id >> 12;
    const int row = id & 4095;                 // b*SEQ + s
    bf16* ptr = qk ? k : q;
    const float* g = qk ? gk : gq;
    const float osc = qk ? 1.0f : 0.08838834764831845f;
    const int s = row & (SEQ - 1);
    const int t = threadIdx.x;
    const int lane = t & 63, wave = t >> 6;

    bf16* base = ptr + (long)row * DIMN + t * 8;
    bf16x8 raw = *(const bf16x8*)base;
    float v[8]; float ss = 0.f;
#pragma unroll
    for (int j = 0; j < 8; j++) { v[j] = (float)raw[j]; ss += v[j] * v[j]; }
#pragma unroll
    for (int off = 32; off; off >>= 1) ss += __shfl_xor(ss, off, 64);
    __shared__ float red[4];
    if (lane == 0) red[wave] = ss;
    __syncthreads();
    float tot = red[0] + red[1] + red[2] + red[3];
    float rn = rsqrtf(tot * (1.0f / DIMN) + 1e-6f);

    const int e0 = t * 8;
    bf16x8 o;
#pragma unroll
    for (int pp = 0; pp < 4; pp++) {
        int e = e0 + pp * 2;
        float xr = v[pp * 2]     * rn * g[e];
        float xi = v[pp * 2 + 1] * rn * g[e + 1];
        int lc = (e >> 1) & 63;
        float cr = freqs[s * 128 + lc * 2];
        float ci = freqs[s * 128 + lc * 2 + 1];
        o[pp * 2]     = (bf16)((xr * cr - xi * ci) * osc);
        o[pp * 2 + 1] = (bf16)((xr * ci + xi * cr) * osc);
    }
    *(bf16x8*)base = o;
}

// -------- flash-style attention v4 (unchanged from r6: 87 µs, FETCH 24.6 MB):
// 8 waves x BM=32/wave, dbuf K/V with prefetch issued AFTER the barrier,
// grid (x=bh, y=qt) keeps a head's K/V XCD-local.
__global__ __launch_bounds__(512, 2) void attention(
    const bf16* __restrict__ Q, const bf16* __restrict__ Kb,
    const bf16* __restrict__ Vt, bf16* __restrict__ O)
{
    __shared__ __attribute__((aligned(16))) bf16 Ksh[2][64 * 128];   // [kr][d], seg^=(kr&15)
    __shared__ __attribute__((aligned(16))) bf16 Vsh[2][128 * 64];   // [d][kr], seg^=(d&7)
    __shared__ __attribute__((aligned(16))) bf16 Psh[8][32 * 72];    // per-wave P[m][kr]
    __shared__ float Lsh[8][32];

    const int t = threadIdx.x;
    const int lane = t & 63, w = t >> 6;
    const int l15 = lane & 15, quad = lane >> 4;
    const int bh = blockIdx.x, b = bh >> 4, h = bh & 15;
    const int qt = blockIdx.y;
    const long qrow0 = (long)b * SEQ + qt * 256 + w * 32;
    const bf16* qbase = Q  + qrow0 * DIMN + h * HD;
    const bf16* kbase = Kb + (long)b * SEQ * DIMN + h * HD;
    const bf16* vbase = Vt + (long)bh * HD * SEQ;

    bf16x8 qf[2][4];
#pragma unroll
    for (int im = 0; im < 2; im++)
#pragma unroll
        for (int kd = 0; kd < 4; kd++)
            qf[im][kd] = *(const bf16x8*)(qbase + (long)(im * 16 + l15) * DIMN + kd * 32 + quad * 8);

    long koff[2], voff[2];
#pragma unroll
    for (int it = 0; it < 2; it++) {
        int fs = it * 512 + t;
        int kr = fs >> 4, kp = fs & 15;
        koff[it] = (long)kr * DIMN + (kp ^ (kr & 15)) * 8;
        int dr = fs >> 3, vp = fs & 7;
        voff[it] = (long)dr * SEQ + (vp ^ (dr & 7)) * 8;
    }

    f32x4 o_acc[2][8] = {};
    float Lt[2] = {0.f, 0.f};

#pragma unroll
    for (int it = 0; it < 2; it++) {
        gld_lds16(kbase + koff[it], &Ksh[0][(it * 512 + t) * 8]);
        gld_lds16(vbase + voff[it], &Vsh[0][(it * 512 + t) * 8]);
    }

    for (int kt = 0; kt < 32; kt++) {
        const int cur = kt & 1;
        __syncthreads();   // drains cur's DMA; fences buf^1 reuse
        if (kt < 31) {
            const bf16* kg = kbase + (long)((kt + 1) * 64) * DIMN;
            const bf16* vg = vbase + (kt + 1) * 64;
#pragma unroll
            for (int it = 0; it < 2; it++) {
                gld_lds16(kg + koff[it], &Ksh[cur ^ 1][(it * 512 + t) * 8]);
                gld_lds16(vg + voff[it], &Vsh[cur ^ 1][(it * 512 + t) * 8]);
            }
        }
        const bf16* K0 = Ksh[cur];
        const bf16* V0 = Vsh[cur];

        // ---- S^T = K Q^T ----
        f32x4 st[4][2] = {};
#pragma unroll
        for (int jk = 0; jk < 4; jk++)
#pragma unroll
            for (int kd = 0; kd < 4; kd++) {
                bf16x8 kf = *(const bf16x8*)(K0 + (jk * 16 + l15) * 128 + (((kd * 4 + quad) ^ l15) & 15) * 8);
                st[jk][0] = __builtin_amdgcn_mfma_f32_16x16x32_bf16(kf, qf[0][kd], st[jk][0], 0, 0, 0);
                st[jk][1] = __builtin_amdgcn_mfma_f32_16x16x32_bf16(kf, qf[1][kd], st[jk][1], 0, 0, 0);
            }

        // ---- exp + P->LDS (b64) + per-lane partial L ----
#pragma unroll
        for (int im = 0; im < 2; im++) {
            float part = 0.f;
#pragma unroll
            for (int jk = 0; jk < 4; jk++) {
                bf16x4 pk;
#pragma unroll
                for (int r = 0; r < 4; r++) {
                    float e = __expf(st[jk][im][r]);
                    part += e;
                    pk[r] = (bf16)e;
                }
                *(bf16x4*)(Psh[w] + (im * 16 + l15) * 72 + jk * 16 + quad * 4) = pk;
            }
            Lt[im] += part;
        }

        // ---- O += P V ----
#pragma unroll
        for (int kd2 = 0; kd2 < 2; kd2++) {
            bf16x8 pa[2];
            pa[0] = *(const bf16x8*)(Psh[w] + (l15)      * 72 + kd2 * 32 + quad * 8);
            pa[1] = *(const bf16x8*)(Psh[w] + (16 + l15) * 72 + kd2 * 32 + quad * 8);
#pragma unroll
            for (int dj = 0; dj < 8; dj++) {
                bf16x8 vfr = *(const bf16x8*)(V0 + (dj * 16 + l15) * 64 + (((kd2 * 4 + quad) ^ l15) & 7) * 8);
                o_acc[0][dj] = __builtin_amdgcn_mfma_f32_16x16x32_bf16(pa[0], vfr, o_acc[0][dj], 0, 0, 0);
                o_acc[1][dj] = __builtin_amdgcn_mfma_f32_16x16x32_bf16(pa[1], vfr, o_acc[1][dj], 0, 0, 0);
            }
        }
    }

#pragma unroll
    for (int im = 0; im < 2; im++) {
        Lt[im] += __shfl_xor(Lt[im], 16, 64);
        Lt[im] += __shfl_xor(Lt[im], 32, 64);
    }
    if (quad == 0) { Lsh[w][l15] = Lt[0]; Lsh[w][16 + l15] = Lt[1]; }

#pragma unroll
    for (int im = 0; im < 2; im++)
#pragma unroll
        for (int r = 0; r < 4; r++) {
            float inv = 1.0f / Lsh[w][im * 16 + quad * 4 + r];
            long orow = qrow0 + im * 16 + quad * 4 + r;
#pragma unroll
            for (int dj = 0; dj < 8; dj++)
                O[orow * DIMN + h * HD + dj * 16 + l15] = (bf16)(o_acc[im][dj][r] * inv);
        }
}

extern "C" void kernel_launch(void* const* d_in, const int* in_sizes, int n_in,
                              void* d_out, int out_size, void* d_ws, size_t ws_size,
                              hipStream_t stream) {
    const float* x     = (const float*)d_in[0];
    const float* freqs = (const float*)d_in[1];
    const float* wq    = (const float*)d_in[2];
    const float* bq    = (const float*)d_in[3];
    const float* wk    = (const float*)d_in[4];
    const float* bk    = (const float*)d_in[5];
    const float* wv    = (const float*)d_in[6];
    const float* bv    = (const float*)d_in[7];
    const float* wo    = (const float*)d_in[8];
    const float* bo    = (const float*)d_in[9];
    const float* gq    = (const float*)d_in[10];
    const float* gk    = (const float*)d_in[11];
    float* out = (float*)d_out;

    const size_t MAT  = (size_t)4096 * 2048 * 2;   // 16 MiB
    const size_t WMAT = (size_t)2048 * 2048 * 2;   // 8 MiB
    char* p = (char*)d_ws;
    bf16* xb  = (bf16*)p; p += MAT;
    bf16* wqb = (bf16*)p; p += WMAT;
    bf16* wkb = (bf16*)p; p += WMAT;
    bf16* wvb = (bf16*)p; p += WMAT;
    bf16* wob = (bf16*)p; p += WMAT;
    bf16* qb  = (bf16*)p; p += MAT;
    bf16* kb  = (bf16*)p; p += MAT;
    bf16* vt  = (bf16*)p; p += MAT;
    bf16* attn = qb;   // alias (safe: per-block exclusive row/col regions)

    cast_all<<<24576, 256, 0, stream>>>(x, wq, wk, wv, wo, xb, wqb, wkb, wvb, wob);

    // fused QKV projection; z==2 writes V^T directly
    gemm_qkv<<<dim3(16, 32, 3), 256, 0, stream>>>(xb, wqb, wkb, wvb,
                                                  bq, bk, bv, qb, kb, vt);

    rmsnorm_rope<<<8192, 256, 0, stream>>>(qb, kb, gq, gk, freqs);
    attention<<<dim3(32, 8), 512, 0, stream>>>(qb, kb, vt, attn);
    gemm_out<<<dim3(16, 32), 256, 0, stream>>>(attn, wob, bo, out);
}